// Round 6
// baseline (95.114 us; speedup 1.0000x reference)
//
#include <hip/hip_runtime.h>

#define HW    (128*128)
#define DHW   (128*128*128)
#define NTOT  (4*DHW)
#define NBLK  2048         // reduce blocks: 4 batches * 16 z-chunks(8z) * 32 y-tiles(4y)
#define TOTB  (NBLK + 4)

__device__ __forceinline__ float sigf(float x){ return 1.0f/(1.0f+__expf(-x)); }
__device__ __forceinline__ float4 ld4(const float* p){ return *(const float4*)p; }

// Self-resetting done counter (wraps mod TOTB each launch; zero-init at load).
__device__ unsigned g_done = 0;

// ws float layout: p_occ[NBLK], p_surf[NBLK], p_over[NBLK], p_trap[4]
//
// R5 post-mortem: four different reduce paths all land ~84us -> mega_k is
// near its HBM floor; remaining controllable cost is finalize_k + its launch
// gap. Fusion WITHOUT R3's mistake: partials via agent-scope RELAXED atomic
// stores (sc-flagged, go to coherence point, no L2 dirtying), ordered before
// a RELAXED done-counter fetch_add by a bare s_waitcnt vmcnt(0) (no release
// -> no buffer_wbl2; no acquire -> no L2 invalidate on 2051/2052 blocks).
// Last block reads partials with sc-flagged loads and writes out[0..1].
__global__ __launch_bounds__(256, 4) void mega_k(
    const float* __restrict__ v, float* p_occ,
    float* p_surf, float* p_over,
    float* p_trap, float* __restrict__ out)
{
    __shared__ float4 smem4[1445];          // 5780 floats (trap needs all of it)
    __shared__ float sred[16];
    __shared__ double sm2[3][4];
    __shared__ unsigned s_last;
    float* smem = (float*)smem4;

    const int bid = blockIdx.x;
    const int tid = threadIdx.x;
    const float4 zero4 = make_float4(0,0,0,0);

    if (bid < 4) {
        // ================= trap box path (unchanged, verified) =============
        const int b = bid;
        const size_t gb = (size_t)b * DHW;
        const int ty = tid & 15, tz = tid >> 4;
        const float a_lo = sigf(-10.0f), a_hi = sigf(10.0f);
        #define M(zz,yy) (smem + (((zz)*17 + (yy))*20))

        float m[16], nv[16];
        {
            const float* rv = v + gb + ((size_t)tz*128 + ty)*128;
            int dzy = abs(tz-5) + abs(ty-5);
            #pragma unroll
            for (int q = 0; q < 4; ++q) {
                int x4 = 4*q;
                float4 a = ld4(rv + x4);
                nv[x4+0]=1.f-a.x; nv[x4+1]=1.f-a.y; nv[x4+2]=1.f-a.z; nv[x4+3]=1.f-a.w;
                int d0=dzy+abs(x4+0-5), d1=dzy+abs(x4+1-5);
                int d2=dzy+abs(x4+2-5), d3=dzy+abs(x4+3-5);
                m[x4+0] = ((d0==0)?1.f:((d0==1)?a_hi:a_lo)) * nv[x4+0];
                m[x4+1] = ((d1==0)?1.f:((d1==1)?a_hi:a_lo)) * nv[x4+1];
                m[x4+2] = ((d2==0)?1.f:((d2==1)?a_hi:a_lo)) * nv[x4+2];
                m[x4+3] = ((d3==0)?1.f:((d3==1)?a_hi:a_lo)) * nv[x4+3];
                *(float4*)(M(tz,ty) + x4) = make_float4(m[x4+0],m[x4+1],m[x4+2],m[x4+3]);
            }
        }
        const float xrE = a_lo * (1.f - v[gb + ((size_t)tz*128 + ty)*128 + 16]);
        {
            int a = tid >> 4, e = tid & 15;
            M(16,a)[e] = a_lo * (1.f - v[gb + ((size_t)16*128 + a)*128 + e]);
            M(a,16)[e] = a_lo * (1.f - v[gb + ((size_t)a*128 + 16)*128 + e]);
        }
        __syncthreads();

        for (int it = 0; it < 9; ++it) {
            const float* YM = M(tz,ty-1);
            const float* YP = M(tz,ty+1);
            const float* ZM = M(tz-1,ty);
            const float* ZP = M(tz+1,ty);
            float nm[16];
            #pragma unroll
            for (int q = 0; q < 4; ++q) {
                int x4 = 4*q;
                float4 ym = (ty > 0) ? *(const float4*)(YM + x4) : zero4;
                float4 yp = *(const float4*)(YP + x4);
                float4 zm = (tz > 0) ? *(const float4*)(ZM + x4) : zero4;
                float4 zp = *(const float4*)(ZP + x4);
                float xl = (q == 0) ? 0.f : m[x4-1];
                float xr = (q == 3) ? xrE : m[x4+4];
                float s0 = xl      + m[x4+1] + ym.x + yp.x + zm.x + zp.x;
                float s1 = m[x4+0] + m[x4+2] + ym.y + yp.y + zm.y + zp.y;
                float s2 = m[x4+1] + m[x4+3] + ym.z + yp.z + zm.z + zp.z;
                float s3 = m[x4+2] + xr      + ym.w + yp.w + zm.w + zp.w;
                nm[x4+0] = fmaxf(m[x4+0], sigf(20.f*s0 - 10.f)) * nv[x4+0];
                nm[x4+1] = fmaxf(m[x4+1], sigf(20.f*s1 - 10.f)) * nv[x4+1];
                nm[x4+2] = fmaxf(m[x4+2], sigf(20.f*s2 - 10.f)) * nv[x4+2];
                nm[x4+3] = fmaxf(m[x4+3], sigf(20.f*s3 - 10.f)) * nv[x4+3];
            }
            __syncthreads();
            float* W = M(tz,ty);
            #pragma unroll
            for (int q = 0; q < 4; ++q) {
                int x4 = 4*q;
                *(float4*)(W + x4) = make_float4(nm[x4+0],nm[x4+1],nm[x4+2],nm[x4+3]);
                m[x4+0]=nm[x4+0]; m[x4+1]=nm[x4+1]; m[x4+2]=nm[x4+2]; m[x4+3]=nm[x4+3];
            }
            __syncthreads();
        }

        float d = 0.f;
        #pragma unroll
        for (int x = 0; x < 16; ++x) d += m[x] - a_lo * nv[x];
        #pragma unroll
        for (int o = 32; o; o >>= 1) d += __shfl_down(d, o, 64);
        int lane = tid & 63, wid = tid >> 6;
        if (lane == 0) sred[wid] = d;
        __syncthreads();
        if (tid == 0) {
            float t = sred[0] + sred[1] + sred[2] + sred[3];
            __hip_atomic_store(&p_trap[b], t, __ATOMIC_RELAXED, __HIP_MEMORY_SCOPE_AGENT);
        }
        #undef M
    } else {
        // ================= streaming reduce path (full upfront issue) ======
        const int rid = bid - 4;                 // 0..2047
        const int b   = rid >> 9;                // batch
        const int rem = rid & 511;
        const int z0  = (rem >> 5) * 8;          // 16 z-chunks of 8
        const int y0  = (rem & 31) * 4;          // 32 y-tiles of 4
        const int tx  = tid & 31;                // x column (4 floats)
        const int tz  = tid >> 5;                // 0..7
        const int z   = z0 + tz;
        const int x4  = tx * 4;
        const size_t gb = (size_t)b * DHW;
        const float* cp = v + gb + (size_t)z * HW;   // curr plane z
        const float* bp = cp - HW;                   // below plane z-1
        const bool hasb = (z >= 1);

        // ---- issue ALL 10 loads back-to-back (they stay in flight) ----
        float4 qc0 = ld4(cp + (y0+0)*128 + x4);
        float4 qc1 = ld4(cp + (y0+1)*128 + x4);
        float4 qc2 = ld4(cp + (y0+2)*128 + x4);
        float4 qc3 = ld4(cp + (y0+3)*128 + x4);
        float4 qb0 = zero4, qb1 = zero4, qb2 = zero4,
               qb3 = zero4, qb4 = zero4, qb5 = zero4;
        if (hasb) {
            if (y0 >= 1)   qb0 = ld4(bp + (y0-1)*128 + x4);
            qb1 = ld4(bp + (y0+0)*128 + x4);
            qb2 = ld4(bp + (y0+1)*128 + x4);
            qb3 = ld4(bp + (y0+2)*128 + x4);
            qb4 = ld4(bp + (y0+3)*128 + x4);
            if (y0+4 <= 127) qb5 = ld4(bp + (y0+4)*128 + x4);
        }

        auto xsum = [&](float4 q) -> float4 {
            float ql = __shfl_up(q.w, 1);   if (tx == 0)  ql = 0.f;
            float qr = __shfl_down(q.x, 1); if (tx == 31) qr = 0.f;
            return make_float4(ql+q.x+q.y, q.x+q.y+q.z, q.y+q.z+q.w, q.z+q.w+qr);
        };

        float occ = 0.f, surf = 0.f, over = 0.f;
        const float wz  = (z==0 || z==127) ? 2.f : 3.f;
        const float wx0 = (x4==0)   ? 2.f : 3.f;
        const float wx3 = (x4==124) ? 2.f : 3.f;
        const float inv9 = 1.f/9.f;

        float4 P0 = zero4, P1 = zero4, P2 = zero4, P3 = zero4,
               P4 = zero4, P5 = zero4;
        if (hasb) {
            P0 = xsum(qb0); P1 = xsum(qb1); P2 = xsum(qb2);
            P3 = xsum(qb3); P4 = xsum(qb4); P5 = xsum(qb5);
        }

        #define ROW(i, VAL, PA, PB, PC)                                        \
        {                                                                      \
            const int y = y0 + (i);                                            \
            occ += VAL.x + VAL.y + VAL.z + VAL.w;                              \
            float wy = (y==0 || y==127) ? 2.f : 3.f;                           \
            surf += wz*wy*(wx0*VAL.x + 3.f*VAL.y + 3.f*VAL.z + wx3*VAL.w);     \
            if (hasb) {                                                        \
                float4 S = make_float4(PA.x+PB.x+PC.x, PA.y+PB.y+PC.y,         \
                                       PA.z+PB.z+PC.z, PA.w+PB.w+PC.w);        \
                over += VAL.x*(1.f - S.x*inv9) + VAL.y*(1.f - S.y*inv9)        \
                      + VAL.z*(1.f - S.z*inv9) + VAL.w*(1.f - S.w*inv9);       \
            }                                                                  \
        }
        ROW(0, qc0, P0, P1, P2)
        ROW(1, qc1, P1, P2, P3)
        ROW(2, qc2, P2, P3, P4)
        ROW(3, qc3, P3, P4, P5)
        #undef ROW

        #pragma unroll
        for (int o = 32; o; o >>= 1) {
            occ  += __shfl_down(occ,  o, 64);
            surf += __shfl_down(surf, o, 64);
            over += __shfl_down(over, o, 64);
        }
        int lane = tid & 63, wid = tid >> 6;
        if (lane == 0) { sred[wid]=occ; sred[4+wid]=surf; sred[8+wid]=over; }
        __syncthreads();
        if (tid == 0) {
            float po = sred[0]+sred[1]+sred[2]+sred[3];
            float ps = sred[4]+sred[5]+sred[6]+sred[7];
            float pv = sred[8]+sred[9]+sred[10]+sred[11];
            // agent-scope relaxed stores: land at the coherence point,
            // no L2 dirtying, no fences.
            __hip_atomic_store(&p_occ [rid], po, __ATOMIC_RELAXED, __HIP_MEMORY_SCOPE_AGENT);
            __hip_atomic_store(&p_surf[rid], ps, __ATOMIC_RELAXED, __HIP_MEMORY_SCOPE_AGENT);
            __hip_atomic_store(&p_over[rid], pv, __ATOMIC_RELAXED, __HIP_MEMORY_SCOPE_AGENT);
        }
    }

    // ================= last-block finalize (no second kernel) ==============
    if (tid == 0) {
        // Order: partial sc-stores must be complete (at coherence point)
        // before our done-increment is visible. Bare vmcnt(0) suffices
        // because the stores are sc-flagged; avoids release's buffer_wbl2.
        asm volatile("s_waitcnt vmcnt(0)" ::: "memory");
        unsigned old = __hip_atomic_fetch_add(&g_done, 1u, __ATOMIC_RELAXED,
                                              __HIP_MEMORY_SCOPE_AGENT);
        s_last = (((old + 1u) % (unsigned)TOTB) == 0u) ? 1u : 0u;
    }
    __syncthreads();
    if (s_last) {
        // all 2052 increments done => all partials at coherence point.
        double occ=0, surf=0, over=0;
        for (int i = tid; i < NBLK; i += 256) {
            occ  += __hip_atomic_load(&p_occ [i], __ATOMIC_RELAXED, __HIP_MEMORY_SCOPE_AGENT);
            surf += __hip_atomic_load(&p_surf[i], __ATOMIC_RELAXED, __HIP_MEMORY_SCOPE_AGENT);
            over += __hip_atomic_load(&p_over[i], __ATOMIC_RELAXED, __HIP_MEMORY_SCOPE_AGENT);
        }
        #pragma unroll
        for (int o = 32; o; o >>= 1) {
            occ  += __shfl_down(occ,  o, 64);
            surf += __shfl_down(surf, o, 64);
            over += __shfl_down(over, o, 64);
        }
        int lane = tid & 63, wid = tid >> 6;
        if (lane == 0) { sm2[0][wid]=occ; sm2[1][wid]=surf; sm2[2][wid]=over; }
        __syncthreads();
        if (tid == 0) {
            double so=0, ss=0, sv=0;
            for (int w = 0; w < 4; ++w) { so+=sm2[0][w]; ss+=sm2[1][w]; sv+=sm2[2][w]; }
            double dS = 0;
            for (int b = 0; b < 4; ++b)
                dS += (double)__hip_atomic_load(&p_trap[b], __ATOMIC_RELAXED, __HIP_MEMORY_SCOPE_AGENT);
            double a_lo = 1.0 / (1.0 + exp(10.0));
            double N = (double)NTOT;
            double trap_sum = a_lo * (N - so) + dS;
            double occupancy = so / N;
            double occ_pen = 10.0 * (occupancy - 0.5) * (occupancy - 0.5);
            out[0] = (float)(sv / N);
            out[1] = (float)(ss / 27.0 / N - 100.0 * trap_sum / N - occ_pen);
        }
    }
}

extern "C" void kernel_launch(void* const* d_in, const int* in_sizes, int n_in,
                              void* d_out, int out_size, void* d_ws, size_t ws_size,
                              hipStream_t stream)
{
    const float* v = (const float*)d_in[0];
    float* out = (float*)d_out;
    float* ws = (float*)d_ws;

    float* p_occ  = ws;
    float* p_surf = p_occ  + NBLK;
    float* p_over = p_surf + NBLK;
    float* p_trap = p_over + NBLK;   // 4 floats

    mega_k<<<TOTB, 256, 0, stream>>>(v, p_occ, p_surf, p_over, p_trap, out);
}

// Round 7
// 83.752 us; speedup vs baseline: 1.1357x; 1.1357x over previous
//
#include <hip/hip_runtime.h>

#define HW    (128*128)
#define DHW   (128*128*128)
#define NTOT  (4*DHW)
#define NBLK  2048         // reduce blocks: 4 batches * 16 z-chunks(8z) * 32 y-tiles(4y)
#define TOTB  (NBLK + 4)

__device__ __forceinline__ float sigf(float x){ return 1.0f/(1.0f+__expf(-x)); }
__device__ __forceinline__ float4 ld4(const float* p){ return *(const float4*)p; }

// ws float layout: p_occ[NBLK], p_surf[NBLK], p_over[NBLK], p_trap[4]
//
// FINAL (revert to R5 = best verified 84.08us). Session matrix:
//   two-kernel structure: 83.4-85.6 for FOUR different reduce paths
//   (spilling / LDS-barrier / rolling / full-MLP) -> mega_k duration has
//   near-zero marginal effect on dur_us.
//   atomic-fused finalize: +11..+14us penalty (R3 acq_rel, R6 relaxed-sc) --
//   any cross-block coherence inside one kernel loses on gfx950's
//   non-coherent per-XCD L2s; the kernel boundary pays the fence once.
// Timed region is dominated by the harness 256-MiB poison fill (43-46us at
// 76-79% of HBM write peak = its own roofline) + reset dispatch spam.
__global__ __launch_bounds__(256, 4) void mega_k(
    const float* __restrict__ v, float* __restrict__ p_occ,
    float* __restrict__ p_surf, float* __restrict__ p_over,
    float* __restrict__ p_trap)
{
    __shared__ float4 smem4[1445];          // 5780 floats (trap needs all of it)
    __shared__ float sred[16];
    float* smem = (float*)smem4;

    const int bid = blockIdx.x;
    const int tid = threadIdx.x;
    const float4 zero4 = make_float4(0,0,0,0);

    if (bid < 4) {
        // ================= trap box path (unchanged, verified) =============
        const int b = bid;
        const size_t gb = (size_t)b * DHW;
        const int ty = tid & 15, tz = tid >> 4;
        const float a_lo = sigf(-10.0f), a_hi = sigf(10.0f);
        #define M(zz,yy) (smem + (((zz)*17 + (yy))*20))

        float m[16], nv[16];
        {
            const float* rv = v + gb + ((size_t)tz*128 + ty)*128;
            int dzy = abs(tz-5) + abs(ty-5);
            #pragma unroll
            for (int q = 0; q < 4; ++q) {
                int x4 = 4*q;
                float4 a = ld4(rv + x4);
                nv[x4+0]=1.f-a.x; nv[x4+1]=1.f-a.y; nv[x4+2]=1.f-a.z; nv[x4+3]=1.f-a.w;
                int d0=dzy+abs(x4+0-5), d1=dzy+abs(x4+1-5);
                int d2=dzy+abs(x4+2-5), d3=dzy+abs(x4+3-5);
                m[x4+0] = ((d0==0)?1.f:((d0==1)?a_hi:a_lo)) * nv[x4+0];
                m[x4+1] = ((d1==0)?1.f:((d1==1)?a_hi:a_lo)) * nv[x4+1];
                m[x4+2] = ((d2==0)?1.f:((d2==1)?a_hi:a_lo)) * nv[x4+2];
                m[x4+3] = ((d3==0)?1.f:((d3==1)?a_hi:a_lo)) * nv[x4+3];
                *(float4*)(M(tz,ty) + x4) = make_float4(m[x4+0],m[x4+1],m[x4+2],m[x4+3]);
            }
        }
        const float xrE = a_lo * (1.f - v[gb + ((size_t)tz*128 + ty)*128 + 16]);
        {
            int a = tid >> 4, e = tid & 15;
            M(16,a)[e] = a_lo * (1.f - v[gb + ((size_t)16*128 + a)*128 + e]);
            M(a,16)[e] = a_lo * (1.f - v[gb + ((size_t)a*128 + 16)*128 + e]);
        }
        __syncthreads();

        for (int it = 0; it < 9; ++it) {
            const float* YM = M(tz,ty-1);
            const float* YP = M(tz,ty+1);
            const float* ZM = M(tz-1,ty);
            const float* ZP = M(tz+1,ty);
            float nm[16];
            #pragma unroll
            for (int q = 0; q < 4; ++q) {
                int x4 = 4*q;
                float4 ym = (ty > 0) ? *(const float4*)(YM + x4) : zero4;
                float4 yp = *(const float4*)(YP + x4);
                float4 zm = (tz > 0) ? *(const float4*)(ZM + x4) : zero4;
                float4 zp = *(const float4*)(ZP + x4);
                float xl = (q == 0) ? 0.f : m[x4-1];
                float xr = (q == 3) ? xrE : m[x4+4];
                float s0 = xl      + m[x4+1] + ym.x + yp.x + zm.x + zp.x;
                float s1 = m[x4+0] + m[x4+2] + ym.y + yp.y + zm.y + zp.y;
                float s2 = m[x4+1] + m[x4+3] + ym.z + yp.z + zm.z + zp.z;
                float s3 = m[x4+2] + xr      + ym.w + yp.w + zm.w + zp.w;
                nm[x4+0] = fmaxf(m[x4+0], sigf(20.f*s0 - 10.f)) * nv[x4+0];
                nm[x4+1] = fmaxf(m[x4+1], sigf(20.f*s1 - 10.f)) * nv[x4+1];
                nm[x4+2] = fmaxf(m[x4+2], sigf(20.f*s2 - 10.f)) * nv[x4+2];
                nm[x4+3] = fmaxf(m[x4+3], sigf(20.f*s3 - 10.f)) * nv[x4+3];
            }
            __syncthreads();
            float* W = M(tz,ty);
            #pragma unroll
            for (int q = 0; q < 4; ++q) {
                int x4 = 4*q;
                *(float4*)(W + x4) = make_float4(nm[x4+0],nm[x4+1],nm[x4+2],nm[x4+3]);
                m[x4+0]=nm[x4+0]; m[x4+1]=nm[x4+1]; m[x4+2]=nm[x4+2]; m[x4+3]=nm[x4+3];
            }
            __syncthreads();
        }

        float d = 0.f;
        #pragma unroll
        for (int x = 0; x < 16; ++x) d += m[x] - a_lo * nv[x];
        #pragma unroll
        for (int o = 32; o; o >>= 1) d += __shfl_down(d, o, 64);
        int lane = tid & 63, wid = tid >> 6;
        if (lane == 0) sred[wid] = d;
        __syncthreads();
        if (tid == 0) p_trap[b] = sred[0] + sred[1] + sred[2] + sred[3];
        #undef M
    } else {
        // ================= streaming reduce path (full upfront issue) ======
        const int rid = bid - 4;                 // 0..2047
        const int b   = rid >> 9;                // batch
        const int rem = rid & 511;
        const int z0  = (rem >> 5) * 8;          // 16 z-chunks of 8
        const int y0  = (rem & 31) * 4;          // 32 y-tiles of 4
        const int tx  = tid & 31;                // x column (4 floats)
        const int tz  = tid >> 5;                // 0..7
        const int z   = z0 + tz;
        const int x4  = tx * 4;
        const size_t gb = (size_t)b * DHW;
        const float* cp = v + gb + (size_t)z * HW;   // curr plane z
        const float* bp = cp - HW;                   // below plane z-1
        const bool hasb = (z >= 1);

        // ---- issue ALL 10 loads back-to-back (they stay in flight) ----
        float4 qc0 = ld4(cp + (y0+0)*128 + x4);
        float4 qc1 = ld4(cp + (y0+1)*128 + x4);
        float4 qc2 = ld4(cp + (y0+2)*128 + x4);
        float4 qc3 = ld4(cp + (y0+3)*128 + x4);
        float4 qb0 = zero4, qb1 = zero4, qb2 = zero4,
               qb3 = zero4, qb4 = zero4, qb5 = zero4;
        if (hasb) {
            if (y0 >= 1)   qb0 = ld4(bp + (y0-1)*128 + x4);
            qb1 = ld4(bp + (y0+0)*128 + x4);
            qb2 = ld4(bp + (y0+1)*128 + x4);
            qb3 = ld4(bp + (y0+2)*128 + x4);
            qb4 = ld4(bp + (y0+3)*128 + x4);
            if (y0+4 <= 127) qb5 = ld4(bp + (y0+4)*128 + x4);
        }

        // x-windowed 3-sum of one below row (2 shuffles). tx==0/31 guards
        // also neutralize edge pulls under wave divergence on hasb.
        auto xsum = [&](float4 q) -> float4 {
            float ql = __shfl_up(q.w, 1);   if (tx == 0)  ql = 0.f;
            float qr = __shfl_down(q.x, 1); if (tx == 31) qr = 0.f;
            return make_float4(ql+q.x+q.y, q.x+q.y+q.z, q.y+q.z+q.w, q.z+q.w+qr);
        };

        float occ = 0.f, surf = 0.f, over = 0.f;
        const float wz  = (z==0 || z==127) ? 2.f : 3.f;
        const float wx0 = (x4==0)   ? 2.f : 3.f;
        const float wx3 = (x4==124) ? 2.f : 3.f;
        const float inv9 = 1.f/9.f;

        // consume in issue order: compiler keeps later loads in flight
        float4 P0 = zero4, P1 = zero4, P2 = zero4, P3 = zero4,
               P4 = zero4, P5 = zero4;
        if (hasb) {
            P0 = xsum(qb0); P1 = xsum(qb1); P2 = xsum(qb2);
            P3 = xsum(qb3); P4 = xsum(qb4); P5 = xsum(qb5);
        }

        #define ROW(i, VAL, PA, PB, PC)                                        \
        {                                                                      \
            const int y = y0 + (i);                                            \
            occ += VAL.x + VAL.y + VAL.z + VAL.w;                              \
            float wy = (y==0 || y==127) ? 2.f : 3.f;                           \
            surf += wz*wy*(wx0*VAL.x + 3.f*VAL.y + 3.f*VAL.z + wx3*VAL.w);     \
            if (hasb) {                                                        \
                float4 S = make_float4(PA.x+PB.x+PC.x, PA.y+PB.y+PC.y,         \
                                       PA.z+PB.z+PC.z, PA.w+PB.w+PC.w);        \
                over += VAL.x*(1.f - S.x*inv9) + VAL.y*(1.f - S.y*inv9)        \
                      + VAL.z*(1.f - S.z*inv9) + VAL.w*(1.f - S.w*inv9);       \
            }                                                                  \
        }
        ROW(0, qc0, P0, P1, P2)
        ROW(1, qc1, P1, P2, P3)
        ROW(2, qc2, P2, P3, P4)
        ROW(3, qc3, P3, P4, P5)
        #undef ROW

        #pragma unroll
        for (int o = 32; o; o >>= 1) {
            occ  += __shfl_down(occ,  o, 64);
            surf += __shfl_down(surf, o, 64);
            over += __shfl_down(over, o, 64);
        }
        int lane = tid & 63, wid = tid >> 6;
        if (lane == 0) { sred[wid]=occ; sred[4+wid]=surf; sred[8+wid]=over; }
        __syncthreads();
        if (tid == 0) {
            p_occ [rid] = sred[0]+sred[1]+sred[2]+sred[3];
            p_surf[rid] = sred[4]+sred[5]+sred[6]+sred[7];
            p_over[rid] = sred[8]+sred[9]+sred[10]+sred[11];
        }
    }
}

// ---------------------------------------------------------------------------
// finalize: sum partials (f64), combine with trap deltas.
// trap_sum = a_lo*(N - sum(v)) + sum(box deltas)
// ---------------------------------------------------------------------------
__global__ __launch_bounds__(1024) void finalize_k(
    const float* __restrict__ p_occ, const float* __restrict__ p_surf,
    const float* __restrict__ p_over, const float* __restrict__ p_trap,
    float* __restrict__ out)
{
    double occ=0, surf=0, over=0;
    for (int i = threadIdx.x; i < NBLK; i += 1024) {
        occ += p_occ[i]; surf += p_surf[i]; over += p_over[i];
    }
    __shared__ double sm[3][16];
    #pragma unroll
    for (int o = 32; o; o >>= 1) {
        occ  += __shfl_down(occ,  o, 64);
        surf += __shfl_down(surf, o, 64);
        over += __shfl_down(over, o, 64);
    }
    int lane = threadIdx.x & 63, wid = threadIdx.x >> 6;
    if (lane == 0) { sm[0][wid]=occ; sm[1][wid]=surf; sm[2][wid]=over; }
    __syncthreads();
    if (threadIdx.x == 0) {
        double so=0, ss=0, sv=0;
        for (int w = 0; w < 16; ++w) { so+=sm[0][w]; ss+=sm[1][w]; sv+=sm[2][w]; }
        double dS = (double)p_trap[0] + p_trap[1] + p_trap[2] + p_trap[3];
        double a_lo = 1.0 / (1.0 + exp(10.0));
        double N = (double)NTOT;
        double trap_sum = a_lo * (N - so) + dS;
        double occupancy = so / N;
        double occ_pen = 10.0 * (occupancy - 0.5) * (occupancy - 0.5);
        out[0] = (float)(sv / N);
        out[1] = (float)(ss / 27.0 / N - 100.0 * trap_sum / N - occ_pen);
    }
}

extern "C" void kernel_launch(void* const* d_in, const int* in_sizes, int n_in,
                              void* d_out, int out_size, void* d_ws, size_t ws_size,
                              hipStream_t stream)
{
    const float* v = (const float*)d_in[0];
    float* out = (float*)d_out;
    float* ws = (float*)d_ws;

    float* p_occ  = ws;
    float* p_surf = p_occ  + NBLK;
    float* p_over = p_surf + NBLK;
    float* p_trap = p_over + NBLK;   // 4 floats

    mega_k<<<TOTB, 256, 0, stream>>>(v, p_occ, p_surf, p_over, p_trap);
    finalize_k<<<1, 1024, 0, stream>>>(p_occ, p_surf, p_over, p_trap, out);
}